// Round 4
// baseline (879.472 us; speedup 1.0000x reference)
//
#include <hip/hip_runtime.h>
#include <hip/hip_bf16.h>
#include <cstdint>
#include <cstddef>

#define N_TOK 8192
#define DIM   2048
#define HID   2048
#define NE    8

typedef _Float16 half8  __attribute__((ext_vector_type(8)));
typedef _Float16 half4v __attribute__((ext_vector_type(4)));
typedef float    floatx4 __attribute__((ext_vector_type(4)));

#define LGKM0 asm volatile("s_waitcnt lgkmcnt(0)" ::: "memory")
#define VMC0  asm volatile("s_waitcnt vmcnt(0)" ::: "memory")
#define VMC2  asm volatile("s_waitcnt vmcnt(2)" ::: "memory")
#define VMC4  asm volatile("s_waitcnt vmcnt(4)" ::: "memory")
#define BARR  __builtin_amdgcn_s_barrier()
#define SB0   __builtin_amdgcn_sched_barrier(0)

__device__ inline void gload_lds16(const void* g, void* l) {
    __builtin_amdgcn_global_load_lds(
        (const __attribute__((address_space(1))) unsigned int*)g,
        (__attribute__((address_space(3))) unsigned int*)l, 16, 0, 0);
}

__device__ __forceinline__ half8 mfma16(half8 a, half8 b, floatx4& c) {
    c = __builtin_amdgcn_mfma_f32_16x16x32_f16(a, b, c, 0, 0, 0);
    return a;
}

// ---------------- fused W1+W2 [E][R][C] fp32 -> [E][C][R] fp16 ----------------
__global__ __launch_bounds__(256) void k_prep(const float* __restrict__ W1,
                                              const float* __restrict__ W2,
                                              _Float16* __restrict__ w1t,
                                              _Float16* __restrict__ w2t) {
    __shared__ float tile[64][65];
    int z = blockIdx.z;
    const float* in = (z < 8) ? W1 : W2;
    _Float16* out   = (z < 8) ? w1t : w2t;
    int e  = z & 7;
    int r0 = blockIdx.y * 64;
    int c0 = blockIdx.x * 64;
    int tc = threadIdx.x & 63, tr = threadIdx.x >> 6; // tr 0..3
    const float* ip = in + ((size_t)e * 2048 + r0) * 2048 + c0;
#pragma unroll
    for (int i = 0; i < 16; i++)
        tile[tr + i * 4][tc] = ip[(size_t)(tr + i * 4) * 2048 + tc];
    __syncthreads();
    _Float16* op = out + ((size_t)e * 2048 + c0) * 2048 + r0;
#pragma unroll
    for (int i = 0; i < 16; i++) {
        int cc = tr + i * 4;
        op[(size_t)cc * 2048 + tc] = (_Float16)tile[tc][cc];
    }
}

// ---------------- gate: logits (fp64 accum), top-2, softmax; fuses x->fp16 ----------------
__global__ __launch_bounds__(256) void k_gate(const float* __restrict__ x,
                                              const float* __restrict__ Wg,
                                              const float* __restrict__ bg,
                                              _Float16* __restrict__ xh,
                                              int* __restrict__ te, float* __restrict__ tw,
                                              int* __restrict__ counts) {
    __shared__ float wgs[NE * DIM]; // 64 KB, transposed [e][d]
    for (int i = threadIdx.x; i < NE * DIM; i += 256) {
        float v = Wg[i];                       // Wg[d][e]: d=i>>3, e=i&7
        wgs[(i & 7) * DIM + (i >> 3)] = v;
    }
    __syncthreads();
    int wv = threadIdx.x >> 6, l = threadIdx.x & 63;
#pragma unroll 1
    for (int it = 0; it < 8; ++it) {
        int t = blockIdx.x * 32 + wv * 8 + it;
        const float* xr = x + (size_t)t * DIM;
        double acc[NE] = {0, 0, 0, 0, 0, 0, 0, 0};
#pragma unroll
        for (int i = 0; i < 8; i++) {
            int d0 = i * 256 + l * 4;
            float4 xv = *(const float4*)(xr + d0);
            half4v hv;
            hv[0] = (_Float16)xv.x; hv[1] = (_Float16)xv.y;
            hv[2] = (_Float16)xv.z; hv[3] = (_Float16)xv.w;
            *(half4v*)(xh + (size_t)t * DIM + d0) = hv;
#pragma unroll
            for (int e = 0; e < NE; e++) {
                float4 w4 = *(const float4*)(wgs + e * DIM + d0);
                acc[e] += (double)xv.x * w4.x + (double)xv.y * w4.y +
                          (double)xv.z * w4.z + (double)xv.w * w4.w;
            }
        }
#pragma unroll
        for (int e = 0; e < NE; e++) {
            double v = acc[e];
            v += __shfl_xor(v, 32, 64); v += __shfl_xor(v, 16, 64);
            v += __shfl_xor(v, 8, 64);  v += __shfl_xor(v, 4, 64);
            v += __shfl_xor(v, 2, 64);  v += __shfl_xor(v, 1, 64);
            acc[e] = v;
        }
        if (l == 0) {
            double best0 = -1e300, best1 = -1e300; int i0 = 0, i1 = 0;
#pragma unroll
            for (int e = 0; e < NE; e++) {
                double lg = acc[e] + (double)bg[e];
                if (lg > best0) { best1 = best0; i1 = i0; best0 = lg; i0 = e; }
                else if (lg > best1) { best1 = lg; i1 = e; }
            }
            float d  = expf((float)(best1 - best0));
            float w0 = 1.f / (1.f + d), w1 = d / (1.f + d);
            te[2 * t] = i0; te[2 * t + 1] = i1;
            tw[2 * t] = w0; tw[2 * t + 1] = w1;
            atomicAdd(&counts[i0], 1);
            atomicAdd(&counts[i1], 1);
        }
    }
}

// ---------------- tiny scan ----------------
__global__ void k_scan(const int* __restrict__ counts, int* __restrict__ offs,
                       int* __restrict__ fill) {
    if (threadIdx.x == 0 && blockIdx.x == 0) {
        int s = 0;
        for (int e = 0; e < NE; e++) { offs[e] = s; s += counts[e]; fill[e] = 0; }
        offs[NE] = s;
    }
}

// ---------------- scatter tokens to expert lists ----------------
__global__ __launch_bounds__(256) void k_scatter(const int* __restrict__ te,
                                                 const float* __restrict__ tw,
                                                 const int* __restrict__ offs,
                                                 int* __restrict__ fill,
                                                 int* __restrict__ ltok,
                                                 float* __restrict__ lw,
                                                 int* __restrict__ tslot) {
    int t = blockIdx.x * blockDim.x + threadIdx.x;
    if (t >= N_TOK) return;
#pragma unroll
    for (int k = 0; k < 2; k++) {
        int e = te[2 * t + k];
        int p = atomicAdd(&fill[e], 1);
        int idx = offs[e] + p;
        ltok[idx] = t; lw[idx] = tw[2 * t + k]; tslot[2 * t + k] = idx;
    }
}

// ================= 8-phase 256x256x64 GEMM (T2+T3+T4+T5) =================
// 512 threads = 8 waves (2m x 4n), wave tile 128x64, acc[8][4] of 16x16.
// LDS: As[2][256][64] + Bs[2][256][64] fp16 = 128 KB (double buffer, buf[t&1]).
// Swizzle (both-sides): physical 16B chunk = logical ^ (row&7); staged via
// pre-swizzled global source chunk + linear gload_lds dest (rule 21).
// Per iteration i: consume tiles 2i (buf0: reads at p1 kk0 / p3 kk1) and
// 2i+1 (buf1: p5/p7); stage slots: p1,p2 -> B(2i+1) buf1; p4,p5 -> A(2i+2);
// p6,p7 -> B(2i+2); p8 -> A(2i+3) both halves.  Counted waits: vmcnt(2)@p4,
// vmcnt(4)@p8 guarantee every half >= its read deadline (derivation: each
// staged half has >=4-phase issue->read separation; checkpoints force all but
// the newest 1/2 halves to have landed).  Write-safety: each stage slot is
// after the post-MFMA barrier of the phase whose lgkmcnt retired the last
// reads of that region.

#define STAGE_A(dstAs, bufoff, h, kt, s0, s1)                                   \
    gload_lds16((s0) + (size_t)(kt) * 64, (dstAs) + (bufoff) + (h) * 8192 + sdA); \
    gload_lds16((s1) + (size_t)(kt) * 64, (dstAs) + (bufoff) + (h) * 8192 + sdA + 4096);

template<bool FULL>
__device__ __forceinline__ void kiter(
    int tb, _Float16* As, _Float16* Bs,
    const _Float16* aS0, const _Float16* aS1, const _Float16* aS2, const _Float16* aS3,
    const _Float16* bB, int sdA,
    int rowA0, int rowB0, int cbo0, int cbo1,
    floatx4 (&acc)[8][4])
{
    const int B1 = 16384; // fp16 offset of buffer 1
    half8 a[8], b[4];

    // ---- p1: read buf0 kk0; stage B(tb+1) lo -> buf1 ----
#pragma unroll
    for (int fm = 0; fm < 8; fm++) a[fm] = *(const half8*)(As + rowA0 + fm * 1024 + cbo0);
#pragma unroll
    for (int fn = 0; fn < 4; fn++) b[fn] = *(const half8*)(Bs + rowB0 + fn * 1024 + cbo0);
    STAGE_A(Bs, B1, 0, tb + 1, bB, bB + 131072);
    BARR; LGKM0; SB0;
    __builtin_amdgcn_s_setprio(1);
#pragma unroll
    for (int fm = 0; fm < 4; fm++)
#pragma unroll
        for (int fn = 0; fn < 4; fn++)
            acc[fm][fn] = __builtin_amdgcn_mfma_f32_16x16x32_f16(a[fm], b[fn], acc[fm][fn], 0, 0, 0);
    __builtin_amdgcn_s_setprio(0);
    BARR;

    // ---- p2: stage B(tb+1) hi -> buf1; MFMA fm4-7 kk0 ----
    STAGE_A(Bs, B1, 1, tb + 1, bB + 262144, bB + 393216);
    BARR; LGKM0; SB0;
    __builtin_amdgcn_s_setprio(1);
#pragma unroll
    for (int fm = 4; fm < 8; fm++)
#pragma unroll
        for (int fn = 0; fn < 4; fn++)
            acc[fm][fn] = __builtin_amdgcn_mfma_f32_16x16x32_f16(a[fm], b[fn], acc[fm][fn], 0, 0, 0);
    __builtin_amdgcn_s_setprio(0);
    BARR;

    // ---- p3: read buf0 kk1; MFMA fm0-3 kk1 ----
#pragma unroll
    for (int fm = 0; fm < 8; fm++) a[fm] = *(const half8*)(As + rowA0 + fm * 1024 + cbo1);
#pragma unroll
    for (int fn = 0; fn < 4; fn++) b[fn] = *(const half8*)(Bs + rowB0 + fn * 1024 + cbo1);
    BARR; LGKM0; SB0;
    __builtin_amdgcn_s_setprio(1);
#pragma unroll
    for (int fm = 0; fm < 4; fm++)
#pragma unroll
        for (int fn = 0; fn < 4; fn++)
            acc[fm][fn] = __builtin_amdgcn_mfma_f32_16x16x32_f16(a[fm], b[fn], acc[fm][fn], 0, 0, 0);
    __builtin_amdgcn_s_setprio(0);
    BARR;

    // ---- p4: stage A(tb+2) lo -> buf0; MFMA fm4-7 kk1; vmcnt(2) ----
    if constexpr (FULL) { STAGE_A(As, 0, 0, tb + 2, aS0, aS1); }
    BARR; LGKM0; SB0;
    __builtin_amdgcn_s_setprio(1);
#pragma unroll
    for (int fm = 4; fm < 8; fm++)
#pragma unroll
        for (int fn = 0; fn < 4; fn++)
            acc[fm][fn] = __builtin_amdgcn_mfma_f32_16x16x32_f16(a[fm], b[fn], acc[fm][fn], 0, 0, 0);
    __builtin_amdgcn_s_setprio(0);
    if constexpr (FULL) { VMC2; } else { VMC0; }
    BARR;

    // ---- p5: read buf1 kk0; stage A(tb+2) hi -> buf0 ----
#pragma unroll
    for (int fm = 0; fm < 8; fm++) a[fm] = *(const half8*)(As + B1 + rowA0 + fm * 1024 + cbo0);
#pragma unroll
    for (int fn = 0; fn < 4; fn++) b[fn] = *(const half8*)(Bs + B1 + rowB0 + fn * 1024 + cbo0);
    if constexpr (FULL) { STAGE_A(As, 0, 1, tb + 2, aS2, aS3); }
    BARR; LGKM0; SB0;
    __builtin_amdgcn_s_setprio(1);
#pragma unroll
    for (int fm = 0; fm < 4; fm++)
#pragma unroll
        for (int fn = 0; fn < 4; fn++)
            acc[fm][fn] = __builtin_amdgcn_mfma_f32_16x16x32_f16(a[fm], b[fn], acc[fm][fn], 0, 0, 0);
    __builtin_amdgcn_s_setprio(0);
    BARR;

    // ---- p6: stage B(tb+2) lo -> buf0; MFMA fm4-7 kk0 ----
    if constexpr (FULL) { STAGE_A(Bs, 0, 0, tb + 2, bB, bB + 131072); }
    BARR; LGKM0; SB0;
    __builtin_amdgcn_s_setprio(1);
#pragma unroll
    for (int fm = 4; fm < 8; fm++)
#pragma unroll
        for (int fn = 0; fn < 4; fn++)
            acc[fm][fn] = __builtin_amdgcn_mfma_f32_16x16x32_f16(a[fm], b[fn], acc[fm][fn], 0, 0, 0);
    __builtin_amdgcn_s_setprio(0);
    BARR;

    // ---- p7: read buf1 kk1; stage B(tb+2) hi -> buf0 ----
#pragma unroll
    for (int fm = 0; fm < 8; fm++) a[fm] = *(const half8*)(As + B1 + rowA0 + fm * 1024 + cbo1);
#pragma unroll
    for (int fn = 0; fn < 4; fn++) b[fn] = *(const half8*)(Bs + B1 + rowB0 + fn * 1024 + cbo1);
    if constexpr (FULL) { STAGE_A(Bs, 0, 1, tb + 2, bB + 262144, bB + 393216); }
    BARR; LGKM0; SB0;
    __builtin_amdgcn_s_setprio(1);
#pragma unroll
    for (int fm = 0; fm < 4; fm++)
#pragma unroll
        for (int fn = 0; fn < 4; fn++)
            acc[fm][fn] = __builtin_amdgcn_mfma_f32_16x16x32_f16(a[fm], b[fn], acc[fm][fn], 0, 0, 0);
    __builtin_amdgcn_s_setprio(0);
    BARR;

    // ---- p8: stage A(tb+3) both halves -> buf1; MFMA fm4-7 kk1; vmcnt(4) ----
    if constexpr (FULL) {
        STAGE_A(As, B1, 0, tb + 3, aS0, aS1);
        STAGE_A(As, B1, 1, tb + 3, aS2, aS3);
    }
    BARR; LGKM0; SB0;
    __builtin_amdgcn_s_setprio(1);
#pragma unroll
    for (int fm = 4; fm < 8; fm++)
#pragma unroll
        for (int fn = 0; fn < 4; fn++)
            acc[fm][fn] = __builtin_amdgcn_mfma_f32_16x16x32_f16(a[fm], b[fn], acc[fm][fn], 0, 0, 0);
    __builtin_amdgcn_s_setprio(0);
    if constexpr (FULL) { VMC4; }
    BARR;
}

template<int LAYER>
__global__ __launch_bounds__(512, 2) void k_gemm(const _Float16* __restrict__ Ain,
                                                 const _Float16* __restrict__ Bt,
                                                 const float* __restrict__ bias,
                                                 const int* __restrict__ counts,
                                                 const int* __restrict__ offs,
                                                 const int* __restrict__ ltok,
                                                 const float* __restrict__ lw,
                                                 _Float16* __restrict__ Cout) {
    __shared__ _Float16 As[2 * 256 * 64];
    __shared__ _Float16 Bs[2 * 256 * 64];

    int e = blockIdx.z;
    int cnt = counts[e];
    int m0 = blockIdx.y * 256;
    if (m0 >= cnt) return;
    int n0 = blockIdx.x * 256;
    int base = offs[e];

    int tid = threadIdx.x;
    int l = tid & 63;
    int wid = tid >> 6;
    int wm = wid >> 2, wn = wid & 3;
    int lr = l & 15, lk = l >> 4;
    int cbo0 = ((lk) ^ (lr & 7)) * 8;      // kk=0 logical chunk lk
    int cbo1 = ((4 + lk) ^ (lr & 7)) * 8;  // kk=1 logical chunk 4+lk
    int rowA0 = (wm * 128 + lr) * 64;
    int rowB0 = (wn * 64 + lr) * 64;

    // staging geometry: thread covers rows srow + j*64 (j=0..3), chunk tid&7
    int srow = tid >> 3;                                  // 0..63
    int c    = tid & 7;
    int sdA  = srow * 64 + c * 8;                         // LDS dest (fp16)
    size_t koff = (size_t)((c ^ (srow & 7)) * 8);         // pre-swizzled src chunk
    const _Float16* aS[4];
#pragma unroll
    for (int j = 0; j < 4; j++) {
        int r = m0 + srow + j * 64; if (r > cnt - 1) r = cnt - 1;
        if constexpr (LAYER == 1) {
            int tok = ltok[base + r];
            aS[j] = Ain + (size_t)tok * DIM + koff;
        } else {
            aS[j] = Ain + (size_t)(base + r) * HID + koff;
        }
    }
    const _Float16* bB = Bt + ((size_t)(e * 2048 + n0 + srow)) * 2048 + koff;

    floatx4 acc[8][4];
#pragma unroll
    for (int m = 0; m < 8; m++)
#pragma unroll
        for (int n = 0; n < 4; n++) acc[m][n] = (floatx4){0.f, 0.f, 0.f, 0.f};

    // prologue: tile0 (A,B -> buf0), tile1 A -> buf1; then vmcnt(4): tile0 landed
    STAGE_A(As, 0, 0, 0, aS[0], aS[1]);
    STAGE_A(As, 0, 1, 0, aS[2], aS[3]);
    STAGE_A(Bs, 0, 0, 0, bB, bB + 131072);
    STAGE_A(Bs, 0, 1, 0, bB + 262144, bB + 393216);
    STAGE_A(As, 16384, 0, 1, aS[0], aS[1]);
    STAGE_A(As, 16384, 1, 1, aS[2], aS[3]);
    VMC4;
    BARR;

#pragma unroll 1
    for (int i = 0; i < 15; i++)
        kiter<true>(2 * i, As, Bs, aS[0], aS[1], aS[2], aS[3], bB, sdA,
                    rowA0, rowB0, cbo0, cbo1, acc);
    kiter<false>(30, As, Bs, aS[0], aS[1], aS[2], aS[3], bB, sdA,
                 rowA0, rowB0, cbo0, cbo1, acc);

    // epilogue
#pragma unroll
    for (int fm = 0; fm < 8; fm++) {
        int row0 = m0 + wm * 128 + fm * 16 + lk * 4;
#pragma unroll
        for (int fn = 0; fn < 4; fn++) {
            int col = n0 + wn * 64 + fn * 16 + lr;
            float bv = bias[e * 2048 + col];
#pragma unroll
            for (int r = 0; r < 4; r++) {
                int row = row0 + r;
                if (row < cnt) {
                    float v = acc[fm][fn][r] + bv;
                    if constexpr (LAYER == 1) {
                        v = v > 0.f ? v : 0.f;
                    } else {
                        v *= lw[base + row];
                    }
                    Cout[(size_t)(base + row) * HID + col] = (_Float16)v;
                }
            }
        }
    }
}

// ---------------- combine the two weighted expert rows per token ----------------
__global__ __launch_bounds__(256) void k_combine(const _Float16* __restrict__ yb,
                                                 const int* __restrict__ tslot,
                                                 float* __restrict__ out) {
    int t = blockIdx.x;
    int s0 = tslot[2 * t], s1 = tslot[2 * t + 1];
    int c = threadIdx.x * 8;
    half8 y0 = *(const half8*)&yb[(size_t)s0 * HID + c];
    half8 y1 = *(const half8*)&yb[(size_t)s1 * HID + c];
    float* op = out + (size_t)t * HID + c;
    float4 o;
    o.x = (float)y0[0] + (float)y1[0];
    o.y = (float)y0[1] + (float)y1[1];
    o.z = (float)y0[2] + (float)y1[2];
    o.w = (float)y0[3] + (float)y1[3];
    *(float4*)(op) = o;
    o.x = (float)y0[4] + (float)y1[4];
    o.y = (float)y0[5] + (float)y1[5];
    o.z = (float)y0[6] + (float)y1[6];
    o.w = (float)y0[7] + (float)y1[7];
    *(float4*)(op + 4) = o;
}

extern "C" void kernel_launch(void* const* d_in, const int* in_sizes, int n_in,
                              void* d_out, int out_size, void* d_ws, size_t ws_size,
                              hipStream_t stream) {
    const float* x  = (const float*)d_in[0];
    const float* Wg = (const float*)d_in[1];
    const float* bg = (const float*)d_in[2];
    const float* W1 = (const float*)d_in[3];
    const float* b1 = (const float*)d_in[4];
    const float* W2 = (const float*)d_in[5];
    const float* b2 = (const float*)d_in[6];
    float* out = (float*)d_out;

    char* ws = (char*)d_ws;
    _Float16* xh  = (_Float16*)(ws);                       // 33,554,432 B
    _Float16* w1t = (_Float16*)(ws + 33554432ULL);         // 67,108,864 B
    _Float16* w2t = (_Float16*)(ws + 100663296ULL);        // 67,108,864 B
    _Float16* hb  = (_Float16*)(ws + 167772160ULL);        // 67,108,864 B
    _Float16* yb  = (_Float16*)(ws + 234881024ULL);        // 67,108,864 B
    char* rt = ws + 301989888ULL;
    int*   counts = (int*)(rt);             // 8 ints
    int*   fill   = (int*)(rt + 32);        // 8 ints
    int*   offs   = (int*)(rt + 64);        // 9 ints
    int*   te     = (int*)(rt + 128);
    float* tw     = (float*)(rt + 128 + 65536);
    int*   ltok   = (int*)(rt + 128 + 131072);
    float* lw     = (float*)(rt + 128 + 196608);
    int*   tslot  = (int*)(rt + 128 + 262144);

    hipMemsetAsync(rt, 0, 64, stream);  // counts + fill
    k_prep<<<dim3(32, 32, 16), 256, 0, stream>>>(W1, W2, w1t, w2t);
    k_gate<<<256, 256, 0, stream>>>(x, Wg, bg, xh, te, tw, counts);
    k_scan<<<1, 64, 0, stream>>>(counts, offs, fill);
    k_scatter<<<32, 256, 0, stream>>>(te, tw, offs, fill, ltok, lw, tslot);
    k_gemm<1><<<dim3(8, 64, 8), 512, 0, stream>>>(xh, w1t, b1, counts, offs, ltok, nullptr, hb);
    k_gemm<2><<<dim3(8, 64, 8), 512, 0, stream>>>(hb, w2t, b2, counts, offs, ltok, lw, yb);
    k_combine<<<8192, 256, 0, stream>>>(yb, tslot, out);
}

// Round 5
// 820.328 us; speedup vs baseline: 1.0721x; 1.0721x over previous
//
#include <hip/hip_runtime.h>
#include <hip/hip_bf16.h>
#include <cstdint>
#include <cstddef>

#define N_TOK 8192
#define DIM   2048
#define HID   2048
#define NE    8

typedef _Float16 half8  __attribute__((ext_vector_type(8)));
typedef _Float16 half4v __attribute__((ext_vector_type(4)));
typedef float    floatx4 __attribute__((ext_vector_type(4)));

#define BARR  __builtin_amdgcn_s_barrier()

__device__ inline void gload_lds16(const void* g, void* l) {
    __builtin_amdgcn_global_load_lds(
        (const __attribute__((address_space(1))) unsigned int*)g,
        (__attribute__((address_space(3))) unsigned int*)l, 16, 0, 0);
}

__device__ __forceinline__ floatx4 MF(half8 a, half8 b, floatx4 c) {
    return __builtin_amdgcn_mfma_f32_16x16x32_f16(a, b, c, 0, 0, 0);
}

// ---------------- fused W1+W2 [E][R][C] fp32 -> [E][C][R] fp16 ----------------
__global__ __launch_bounds__(256) void k_prep(const float* __restrict__ W1,
                                              const float* __restrict__ W2,
                                              _Float16* __restrict__ w1t,
                                              _Float16* __restrict__ w2t) {
    __shared__ float tile[64][65];
    int z = blockIdx.z;
    const float* in = (z < 8) ? W1 : W2;
    _Float16* out   = (z < 8) ? w1t : w2t;
    int e  = z & 7;
    int r0 = blockIdx.y * 64;
    int c0 = blockIdx.x * 64;
    int tc = threadIdx.x & 63, tr = threadIdx.x >> 6; // tr 0..3
    const float* ip = in + ((size_t)e * 2048 + r0) * 2048 + c0;
#pragma unroll
    for (int i = 0; i < 16; i++)
        tile[tr + i * 4][tc] = ip[(size_t)(tr + i * 4) * 2048 + tc];
    __syncthreads();
    _Float16* op = out + ((size_t)e * 2048 + c0) * 2048 + r0;
#pragma unroll
    for (int i = 0; i < 16; i++) {
        int cc = tr + i * 4;
        op[(size_t)cc * 2048 + tc] = (_Float16)tile[tc][cc];
    }
}

// ---------------- gate: logits (fp64 accum), top-2, softmax; fuses x->fp16 ----------------
__global__ __launch_bounds__(256) void k_gate(const float* __restrict__ x,
                                              const float* __restrict__ Wg,
                                              const float* __restrict__ bg,
                                              _Float16* __restrict__ xh,
                                              int* __restrict__ te, float* __restrict__ tw,
                                              int* __restrict__ counts) {
    __shared__ float wgs[NE * DIM]; // 64 KB, transposed [e][d]
    for (int i = threadIdx.x; i < NE * DIM; i += 256) {
        float v = Wg[i];                       // Wg[d][e]: d=i>>3, e=i&7
        wgs[(i & 7) * DIM + (i >> 3)] = v;
    }
    __syncthreads();
    int wv = threadIdx.x >> 6, l = threadIdx.x & 63;
#pragma unroll 1
    for (int it = 0; it < 8; ++it) {
        int t = blockIdx.x * 32 + wv * 8 + it;
        const float* xr = x + (size_t)t * DIM;
        double acc[NE] = {0, 0, 0, 0, 0, 0, 0, 0};
#pragma unroll
        for (int i = 0; i < 8; i++) {
            int d0 = i * 256 + l * 4;
            float4 xv = *(const float4*)(xr + d0);
            half4v hv;
            hv[0] = (_Float16)xv.x; hv[1] = (_Float16)xv.y;
            hv[2] = (_Float16)xv.z; hv[3] = (_Float16)xv.w;
            *(half4v*)(xh + (size_t)t * DIM + d0) = hv;
#pragma unroll
            for (int e = 0; e < NE; e++) {
                float4 w4 = *(const float4*)(wgs + e * DIM + d0);
                acc[e] += (double)xv.x * w4.x + (double)xv.y * w4.y +
                          (double)xv.z * w4.z + (double)xv.w * w4.w;
            }
        }
#pragma unroll
        for (int e = 0; e < NE; e++) {
            double v = acc[e];
            v += __shfl_xor(v, 32, 64); v += __shfl_xor(v, 16, 64);
            v += __shfl_xor(v, 8, 64);  v += __shfl_xor(v, 4, 64);
            v += __shfl_xor(v, 2, 64);  v += __shfl_xor(v, 1, 64);
            acc[e] = v;
        }
        if (l == 0) {
            double best0 = -1e300, best1 = -1e300; int i0 = 0, i1 = 0;
#pragma unroll
            for (int e = 0; e < NE; e++) {
                double lg = acc[e] + (double)bg[e];
                if (lg > best0) { best1 = best0; i1 = i0; best0 = lg; i0 = e; }
                else if (lg > best1) { best1 = lg; i1 = e; }
            }
            float d  = expf((float)(best1 - best0));
            float w0 = 1.f / (1.f + d), w1 = d / (1.f + d);
            te[2 * t] = i0; te[2 * t + 1] = i1;
            tw[2 * t] = w0; tw[2 * t + 1] = w1;
            atomicAdd(&counts[i0], 1);
            atomicAdd(&counts[i1], 1);
        }
    }
}

// ---------------- tiny scan ----------------
__global__ void k_scan(const int* __restrict__ counts, int* __restrict__ offs,
                       int* __restrict__ fill) {
    if (threadIdx.x == 0 && blockIdx.x == 0) {
        int s = 0;
        for (int e = 0; e < NE; e++) { offs[e] = s; s += counts[e]; fill[e] = 0; }
        offs[NE] = s;
    }
}

// ---------------- scatter tokens to expert lists ----------------
__global__ __launch_bounds__(256) void k_scatter(const int* __restrict__ te,
                                                 const float* __restrict__ tw,
                                                 const int* __restrict__ offs,
                                                 int* __restrict__ fill,
                                                 int* __restrict__ ltok,
                                                 float* __restrict__ lw,
                                                 int* __restrict__ tslot) {
    int t = blockIdx.x * blockDim.x + threadIdx.x;
    if (t >= N_TOK) return;
#pragma unroll
    for (int k = 0; k < 2; k++) {
        int e = te[2 * t + k];
        int p = atomicAdd(&fill[e], 1);
        int idx = offs[e] + p;
        ltok[idx] = t; lw[idx] = tw[2 * t + k]; tslot[2 * t + k] = idx;
    }
}

// ================= counted-wait pipelined GEMM: BM=BN=256, BK=64 =================
// 512 thr = 8 waves (2m x 4n), wave tile 128x64, acc[8][4] of 16x16x32_f16.
// LDS: As[2][256][64] + Bs[2][256][64] fp16 = 128 KB double buffer.
// Per K-tile: 4 {read-set || MFMA-cluster} interleaved in source order (compiler
// emits counted lgkmcnt -> LDS pipe overlaps MFMA pipe), then:
//   BARR (all reads of buf[t&1] retired) ; stage t+2 -> buf[t&1] ;
//   vmcnt(8) (per-wave proof tile t+1 landed; t+2's 8 loads stay in flight) ; BARR.
// XOR swizzle (both-sides): physical 16B chunk = logical ^ (row&7).

template<int MODE>  // 0: stage t+2 + vmcnt(8); 1: vmcnt(0) (t=NT-2); 2: last tile
__device__ __forceinline__ void gtile(
    _Float16* Ab, _Float16* Bb, int t, int ldst,
    const _Float16* aS0, const _Float16* aS1, const _Float16* aS2, const _Float16* aS3,
    const _Float16* bS0, const _Float16* bS1, const _Float16* bS2, const _Float16* bS3,
    int rA, int rB, int cbo0, int cbo1, floatx4 (&acc)[8][4])
{
    half8 a0[4], a1[4], a2[4], a3[4], b0[4], b1[4];
#pragma unroll
    for (int i = 0; i < 4; i++) a0[i] = *(const half8*)(Ab + rA + i * 1024 + cbo0);
#pragma unroll
    for (int n = 0; n < 4; n++) b0[n] = *(const half8*)(Bb + rB + n * 1024 + cbo0);
#pragma unroll
    for (int i = 0; i < 4; i++) a1[i] = *(const half8*)(Ab + rA + (4 + i) * 1024 + cbo0);
    __builtin_amdgcn_s_setprio(1);
#pragma unroll
    for (int i = 0; i < 4; i++)
#pragma unroll
        for (int n = 0; n < 4; n++) acc[i][n] = MF(a0[i], b0[n], acc[i][n]);
    __builtin_amdgcn_s_setprio(0);
#pragma unroll
    for (int i = 0; i < 4; i++) a2[i] = *(const half8*)(Ab + rA + i * 1024 + cbo1);
#pragma unroll
    for (int n = 0; n < 4; n++) b1[n] = *(const half8*)(Bb + rB + n * 1024 + cbo1);
    __builtin_amdgcn_s_setprio(1);
#pragma unroll
    for (int i = 0; i < 4; i++)
#pragma unroll
        for (int n = 0; n < 4; n++) acc[4 + i][n] = MF(a1[i], b0[n], acc[4 + i][n]);
    __builtin_amdgcn_s_setprio(0);
#pragma unroll
    for (int i = 0; i < 4; i++) a3[i] = *(const half8*)(Ab + rA + (4 + i) * 1024 + cbo1);
    __builtin_amdgcn_s_setprio(1);
#pragma unroll
    for (int i = 0; i < 4; i++)
#pragma unroll
        for (int n = 0; n < 4; n++) acc[i][n] = MF(a2[i], b1[n], acc[i][n]);
#pragma unroll
    for (int i = 0; i < 4; i++)
#pragma unroll
        for (int n = 0; n < 4; n++) acc[4 + i][n] = MF(a3[i], b1[n], acc[4 + i][n]);
    __builtin_amdgcn_s_setprio(0);

    if constexpr (MODE == 2) return;
    BARR;   // all waves done reading buf[t&1] (own reads retired via auto-lgkm)
    if constexpr (MODE == 0) {
        _Float16* Ad = Ab + ldst;
        _Float16* Bd = Bb + ldst;
        gload_lds16(aS0 + (size_t)(t + 2) * 64, Ad);
        gload_lds16(aS1 + (size_t)(t + 2) * 64, Ad + 4096);
        gload_lds16(aS2 + (size_t)(t + 2) * 64, Ad + 8192);
        gload_lds16(aS3 + (size_t)(t + 2) * 64, Ad + 12288);
        gload_lds16(bS0 + (size_t)(t + 2) * 64, Bd);
        gload_lds16(bS1 + (size_t)(t + 2) * 64, Bd + 4096);
        gload_lds16(bS2 + (size_t)(t + 2) * 64, Bd + 8192);
        gload_lds16(bS3 + (size_t)(t + 2) * 64, Bd + 12288);
        asm volatile("s_waitcnt vmcnt(8)" ::: "memory"); // tile t+1 fully landed
    } else {
        asm volatile("s_waitcnt vmcnt(0)" ::: "memory"); // last staged tile landed
    }
    BARR;   // every wave has proven its own tile-(t+1) loads landed
}

template<int LAYER>
__global__ __launch_bounds__(512, 2) void k_gemm(const _Float16* __restrict__ Ain,
                                                 const _Float16* __restrict__ Bt,
                                                 const float* __restrict__ bias,
                                                 const int* __restrict__ counts,
                                                 const int* __restrict__ offs,
                                                 const int* __restrict__ ltok,
                                                 const float* __restrict__ lw,
                                                 _Float16* __restrict__ Cout) {
    __shared__ _Float16 As[2 * 256 * 64];
    __shared__ _Float16 Bs[2 * 256 * 64];

    // XCD-expert affinity: x in [0,64); xs=(x&7)*8+(x>>3): XCD c owns expert c.
    int xs = (blockIdx.x & 7) * 8 + (blockIdx.x >> 3);
    int e  = xs >> 3;
    int n0 = (xs & 7) * 256;
    int cnt = counts[e];
    int m0 = blockIdx.y * 256;
    if (m0 >= cnt) return;
    int base = offs[e];

    int tid = threadIdx.x;
    int l = tid & 63;
    int wid = tid >> 6;
    int wm = wid >> 2, wn = wid & 3;
    int lr = l & 15, lk = l >> 4;
    int cbo0 = ((lk) ^ (lr & 7)) * 8;      // kk=0, logical chunk lk
    int cbo1 = ((4 + lk) ^ (lr & 7)) * 8;  // kk=1, logical chunk 4+lk
    int rA = (wm * 128 + lr) * 64;
    int rB = (wn * 64 + lr) * 64;

    // staging: thread covers rows srow + j*64 (j=0..3), chunk c=tid&7; LDS dest
    // is lane-linear tid*8 halves; global source chunk pre-swizzled by row&7.
    int srow = tid >> 3;
    int c    = tid & 7;
    int ldst = tid * 8;
    size_t koff = (size_t)((c ^ (srow & 7)) * 8);
    const _Float16* aS[4];
#pragma unroll
    for (int j = 0; j < 4; j++) {
        int r = m0 + srow + j * 64; if (r > cnt - 1) r = cnt - 1;
        if constexpr (LAYER == 1) {
            int tok = ltok[base + r];
            aS[j] = Ain + (size_t)tok * DIM + koff;
        } else {
            aS[j] = Ain + (size_t)(base + r) * HID + koff;
        }
    }
    const _Float16* bS[4];
#pragma unroll
    for (int j = 0; j < 4; j++)
        bS[j] = Bt + ((size_t)(e * 2048 + n0 + srow + j * 64)) * 2048 + koff;

    floatx4 acc[8][4];
#pragma unroll
    for (int m = 0; m < 8; m++)
#pragma unroll
        for (int n = 0; n < 4; n++) acc[m][n] = (floatx4){0.f, 0.f, 0.f, 0.f};

    // prologue: stage tile0 -> buf0, tile1 -> buf1 (A first, then B, per tile)
#pragma unroll
    for (int j = 0; j < 4; j++) gload_lds16(aS[j], As + ldst + j * 4096);
#pragma unroll
    for (int j = 0; j < 4; j++) gload_lds16(bS[j], Bs + ldst + j * 4096);
#pragma unroll
    for (int j = 0; j < 4; j++) gload_lds16(aS[j] + 64, As + 16384 + ldst + j * 4096);
#pragma unroll
    for (int j = 0; j < 4; j++) gload_lds16(bS[j] + 64, Bs + 16384 + ldst + j * 4096);
    asm volatile("s_waitcnt vmcnt(8)" ::: "memory"); // tile0 landed
    BARR;

#pragma unroll 1
    for (int i = 0; i < 15; i++) {
        gtile<0>(As, Bs, 2 * i, ldst, aS[0], aS[1], aS[2], aS[3],
                 bS[0], bS[1], bS[2], bS[3], rA, rB, cbo0, cbo1, acc);
        gtile<0>(As + 16384, Bs + 16384, 2 * i + 1, ldst, aS[0], aS[1], aS[2], aS[3],
                 bS[0], bS[1], bS[2], bS[3], rA, rB, cbo0, cbo1, acc);
    }
    gtile<1>(As, Bs, 30, ldst, aS[0], aS[1], aS[2], aS[3],
             bS[0], bS[1], bS[2], bS[3], rA, rB, cbo0, cbo1, acc);
    gtile<2>(As + 16384, Bs + 16384, 31, ldst, aS[0], aS[1], aS[2], aS[3],
             bS[0], bS[1], bS[2], bS[3], rA, rB, cbo0, cbo1, acc);

    // epilogue
#pragma unroll
    for (int fm = 0; fm < 8; fm++) {
        int row0 = m0 + wm * 128 + fm * 16 + lk * 4;
#pragma unroll
        for (int fn = 0; fn < 4; fn++) {
            int col = n0 + wn * 64 + fn * 16 + lr;
            float bv = bias[e * 2048 + col];
#pragma unroll
            for (int r = 0; r < 4; r++) {
                int row = row0 + r;
                if (row < cnt) {
                    float v = acc[fm][fn][r] + bv;
                    if constexpr (LAYER == 1) {
                        v = v > 0.f ? v : 0.f;
                    } else {
                        v *= lw[base + row];
                    }
                    Cout[(size_t)(base + row) * HID + col] = (_Float16)v;
                }
            }
        }
    }
}

// ---------------- combine the two weighted expert rows per token ----------------
__global__ __launch_bounds__(256) void k_combine(const _Float16* __restrict__ yb,
                                                 const int* __restrict__ tslot,
                                                 float* __restrict__ out) {
    int t = blockIdx.x;
    int s0 = tslot[2 * t], s1 = tslot[2 * t + 1];
    int c = threadIdx.x * 8;
    half8 y0 = *(const half8*)&yb[(size_t)s0 * HID + c];
    half8 y1 = *(const half8*)&yb[(size_t)s1 * HID + c];
    float* op = out + (size_t)t * HID + c;
    float4 o;
    o.x = (float)y0[0] + (float)y1[0];
    o.y = (float)y0[1] + (float)y1[1];
    o.z = (float)y0[2] + (float)y1[2];
    o.w = (float)y0[3] + (float)y1[3];
    *(float4*)(op) = o;
    o.x = (float)y0[4] + (float)y1[4];
    o.y = (float)y0[5] + (float)y1[5];
    o.z = (float)y0[6] + (float)y1[6];
    o.w = (float)y0[7] + (float)y1[7];
    *(float4*)(op + 4) = o;
}

extern "C" void kernel_launch(void* const* d_in, const int* in_sizes, int n_in,
                              void* d_out, int out_size, void* d_ws, size_t ws_size,
                              hipStream_t stream) {
    const float* x  = (const float*)d_in[0];
    const float* Wg = (const float*)d_in[1];
    const float* bg = (const float*)d_in[2];
    const float* W1 = (const float*)d_in[3];
    const float* b1 = (const float*)d_in[4];
    const float* W2 = (const float*)d_in[5];
    const float* b2 = (const float*)d_in[6];
    float* out = (float*)d_out;

    char* ws = (char*)d_ws;
    _Float16* xh  = (_Float16*)(ws);                       // 33,554,432 B
    _Float16* w1t = (_Float16*)(ws + 33554432ULL);         // 67,108,864 B
    _Float16* w2t = (_Float16*)(ws + 100663296ULL);        // 67,108,864 B
    _Float16* hb  = (_Float16*)(ws + 167772160ULL);        // 67,108,864 B
    _Float16* yb  = (_Float16*)(ws + 234881024ULL);        // 67,108,864 B
    char* rt = ws + 301989888ULL;
    int*   counts = (int*)(rt);             // 8 ints
    int*   fill   = (int*)(rt + 32);        // 8 ints
    int*   offs   = (int*)(rt + 64);        // 9 ints
    int*   te     = (int*)(rt + 128);
    float* tw     = (float*)(rt + 128 + 65536);
    int*   ltok   = (int*)(rt + 128 + 131072);
    float* lw     = (float*)(rt + 128 + 196608);
    int*   tslot  = (int*)(rt + 128 + 262144);

    hipMemsetAsync(rt, 0, 64, stream);  // counts + fill
    k_prep<<<dim3(32, 32, 16), 256, 0, stream>>>(W1, W2, w1t, w2t);
    k_gate<<<256, 256, 0, stream>>>(x, Wg, bg, xh, te, tw, counts);
    k_scan<<<1, 64, 0, stream>>>(counts, offs, fill);
    k_scatter<<<32, 256, 0, stream>>>(te, tw, offs, fill, ltok, lw, tslot);
    k_gemm<1><<<dim3(64, 64), 512, 0, stream>>>(xh, w1t, b1, counts, offs, ltok, nullptr, hb);
    k_gemm<2><<<dim3(64, 64), 512, 0, stream>>>(hb, w2t, b2, counts, offs, ltok, lw, yb);
    k_combine<<<8192, 256, 0, stream>>>(yb, tslot, out);
}

// Round 6
// 697.469 us; speedup vs baseline: 1.2609x; 1.1761x over previous
//
#include <hip/hip_runtime.h>
#include <hip/hip_bf16.h>
#include <cstdint>
#include <cstddef>

#define N_TOK 8192
#define DIM   2048
#define HID   2048
#define NE    8

typedef _Float16 half8  __attribute__((ext_vector_type(8)));
typedef _Float16 half4v __attribute__((ext_vector_type(4)));
typedef float    floatx4 __attribute__((ext_vector_type(4)));

#define BARR  __builtin_amdgcn_s_barrier()
#define SB0   __builtin_amdgcn_sched_barrier(0)
#define LGKM0 asm volatile("s_waitcnt lgkmcnt(0)" ::: "memory")

__device__ inline void gload_lds16(const void* g, void* l) {
    __builtin_amdgcn_global_load_lds(
        (const __attribute__((address_space(1))) unsigned int*)g,
        (__attribute__((address_space(3))) unsigned int*)l, 16, 0, 0);
}

__device__ __forceinline__ floatx4 MF(half8 a, half8 b, floatx4 c) {
    return __builtin_amdgcn_mfma_f32_16x16x32_f16(a, b, c, 0, 0, 0);
}

// ---------------- fused W1+W2 [E][R][C] fp32 -> [E][C][R] fp16 ----------------
__global__ __launch_bounds__(256) void k_prep(const float* __restrict__ W1,
                                              const float* __restrict__ W2,
                                              _Float16* __restrict__ w1t,
                                              _Float16* __restrict__ w2t) {
    __shared__ float tile[64][65];
    int z = blockIdx.z;
    const float* in = (z < 8) ? W1 : W2;
    _Float16* out   = (z < 8) ? w1t : w2t;
    int e  = z & 7;
    int r0 = blockIdx.y * 64;
    int c0 = blockIdx.x * 64;
    int tc = threadIdx.x & 63, tr = threadIdx.x >> 6;
    const float* ip = in + ((size_t)e * 2048 + r0) * 2048 + c0;
#pragma unroll
    for (int i = 0; i < 16; i++)
        tile[tr + i * 4][tc] = ip[(size_t)(tr + i * 4) * 2048 + tc];
    __syncthreads();
    _Float16* op = out + ((size_t)e * 2048 + c0) * 2048 + r0;
#pragma unroll
    for (int i = 0; i < 16; i++) {
        int cc = tr + i * 4;
        op[(size_t)cc * 2048 + tc] = (_Float16)tile[tc][cc];
    }
}

// ---------------- gate: fp64-accum logits, top-2, softmax; fuses x->fp16 ----------------
__global__ __launch_bounds__(256) void k_gate(const float* __restrict__ x,
                                              const float* __restrict__ Wg,
                                              const float* __restrict__ bg,
                                              _Float16* __restrict__ xh,
                                              int* __restrict__ te, float* __restrict__ tw,
                                              int* __restrict__ counts) {
    __shared__ float wgs[NE * DIM]; // 64 KB, transposed [e][d]
    __shared__ int lcnt[NE];
    if (threadIdx.x < NE) lcnt[threadIdx.x] = 0;
    for (int i = threadIdx.x; i < NE * DIM; i += 256)
        wgs[(i & 7) * DIM + (i >> 3)] = Wg[i];
    __syncthreads();
    int wv = threadIdx.x >> 6, l = threadIdx.x & 63;
#pragma unroll 1
    for (int it = 0; it < 4; ++it) {
        int t = blockIdx.x * 16 + wv * 4 + it;
        const float* xr = x + (size_t)t * DIM;
        double acc[NE] = {0, 0, 0, 0, 0, 0, 0, 0};
#pragma unroll 2
        for (int i = 0; i < 8; i++) {
            int d0 = i * 256 + l * 4;
            float4 xv = *(const float4*)(xr + d0);
            half4v hv;
            hv[0] = (_Float16)xv.x; hv[1] = (_Float16)xv.y;
            hv[2] = (_Float16)xv.z; hv[3] = (_Float16)xv.w;
            *(half4v*)(xh + (size_t)t * DIM + d0) = hv;
#pragma unroll
            for (int e = 0; e < NE; e++) {
                float4 w4 = *(const float4*)(wgs + e * DIM + d0);
                acc[e] += (double)xv.x * w4.x + (double)xv.y * w4.y +
                          (double)xv.z * w4.z + (double)xv.w * w4.w;
            }
        }
#pragma unroll
        for (int e = 0; e < NE; e++) {
            double v = acc[e];
            v += __shfl_xor(v, 32, 64); v += __shfl_xor(v, 16, 64);
            v += __shfl_xor(v, 8, 64);  v += __shfl_xor(v, 4, 64);
            v += __shfl_xor(v, 2, 64);  v += __shfl_xor(v, 1, 64);
            acc[e] = v;
        }
        if (l == 0) {
            double best0 = -1e300, best1 = -1e300; int i0 = 0, i1 = 0;
#pragma unroll
            for (int e = 0; e < NE; e++) {
                double lg = acc[e] + (double)bg[e];
                if (lg > best0) { best1 = best0; i1 = i0; best0 = lg; i0 = e; }
                else if (lg > best1) { best1 = lg; i1 = e; }
            }
            float d  = expf((float)(best1 - best0));
            float w0 = 1.f / (1.f + d), w1 = d / (1.f + d);
            te[2 * t] = i0; te[2 * t + 1] = i1;
            tw[2 * t] = w0; tw[2 * t + 1] = w1;
            atomicAdd(&lcnt[i0], 1);
            atomicAdd(&lcnt[i1], 1);
        }
    }
    __syncthreads();
    if (threadIdx.x < NE) atomicAdd(&counts[threadIdx.x], lcnt[threadIdx.x]);
}

// ---------------- tiny scan ----------------
__global__ void k_scan(const int* __restrict__ counts, int* __restrict__ offs,
                       int* __restrict__ fill) {
    if (threadIdx.x == 0 && blockIdx.x == 0) {
        int s = 0;
        for (int e = 0; e < NE; e++) { offs[e] = s; s += counts[e]; fill[e] = 0; }
        offs[NE] = s;
    }
}

// ---------------- scatter tokens to expert lists ----------------
__global__ __launch_bounds__(256) void k_scatter(const int* __restrict__ te,
                                                 const float* __restrict__ tw,
                                                 const int* __restrict__ offs,
                                                 int* __restrict__ fill,
                                                 int* __restrict__ ltok,
                                                 float* __restrict__ lw,
                                                 int* __restrict__ tslot) {
    int t = blockIdx.x * blockDim.x + threadIdx.x;
    if (t >= N_TOK) return;
#pragma unroll
    for (int k = 0; k < 2; k++) {
        int e = te[2 * t + k];
        int p = atomicAdd(&fill[e], 1);
        int idx = offs[e] + p;
        ltok[idx] = t; lw[idx] = tw[2 * t + k]; tslot[2 * t + k] = idx;
    }
}

// ============ 4-phase/tile 256x256x64 GEMM (T2+T3+T4+T5, ledger-verified) ============
// 512 thr = 8 waves (2m x 4n); wave tile 128x64; acc[8][4] of 16x16x32_f16.
// LDS: As[2][256][64] + Bs[2][256][64] fp16 = 128 KB; tile t -> buf t&1.
// Units (each 16KB, 2 gloads/thread): A-f0 = rows {0-63,128-191} (fm0-3 of both
// wm), A-f1 = rows {64-127,192-255}; B-n0 = rows {wn*64+0..31}, B-n1 = {+32..63}.
// Registers carry: a03 ph1->ph2, b01 ph1->ph3, b23 ph2->ph4, a47 ph3->ph4, so
// each unit's LDS is read in exactly ONE phase -> its slot frees at that
// phase's end barrier.  Phases (each: reads | stage | BARR | lgkm0 | MFMA16):
//  ph1: read a03+b01 (12)            | -           | MFMA fm0-3 x fn0-1
//  ph2: read b23 (4)                 | A-f0(t+2)   | MFMA fm0-3 x fn2-3
//  ph3: read a47 (8)                 | B-n0(t+2)   | MFMA fm4-7 x fn0-1
//  ph4: -                            | A-f1+B-n1   | MFMA fm4-7 x fn2-3; vmcnt(6)
// Ledger: checkpoint at tile-t ph4 forces {B-n0,A-f1,B-n1}(t+1) (issued tile
// t-1, >=6 phases back) + A-f0(t+2); leaves newest 6 loads in flight ->
// tile t+1 fully landed before its reads; no forced unit younger than ~1.5
// tiles -> no latency stall.  XOR swizzle both-sides: LDS[r][c] holds logical
// chunk c^(r&7); reads use ((kk*4+lk)^(lr&7)).

template<int MODE>  // 0: stage t+2 + vmcnt(6); 1: no stage, vmcnt(0); 2: last
__device__ __forceinline__ void tile4(
    const _Float16* __restrict__ Ab, const _Float16* __restrict__ Bb,
    _Float16* Asd, _Float16* Bsd, int kt2,
    const _Float16* aS0, const _Float16* aS1, const _Float16* aS2, const _Float16* aS3,
    const _Float16* bS0, const _Float16* bS1, const _Float16* bS2, const _Float16* bS3,
    int ldA, int sdB, int rA, int rB, int cbo0, int cbo1,
    floatx4 (&acc)[8][4])
{
    half8 a03[4][2], a47[4][2], b01[2][2], b23[2][2];

    // ---- ph1 ----
#pragma unroll
    for (int fm = 0; fm < 4; fm++) {
        a03[fm][0] = *(const half8*)(Ab + rA + fm * 1024 + cbo0);
        a03[fm][1] = *(const half8*)(Ab + rA + fm * 1024 + cbo1);
    }
#pragma unroll
    for (int fn = 0; fn < 2; fn++) {
        b01[fn][0] = *(const half8*)(Bb + rB + fn * 1024 + cbo0);
        b01[fn][1] = *(const half8*)(Bb + rB + fn * 1024 + cbo1);
    }
    asm volatile("s_waitcnt lgkmcnt(8)" ::: "memory");
    BARR; LGKM0; SB0;
    __builtin_amdgcn_s_setprio(1);
#pragma unroll
    for (int fm = 0; fm < 4; fm++)
#pragma unroll
        for (int fn = 0; fn < 2; fn++) {
            acc[fm][fn] = MF(a03[fm][0], b01[fn][0], acc[fm][fn]);
            acc[fm][fn] = MF(a03[fm][1], b01[fn][1], acc[fm][fn]);
        }
    __builtin_amdgcn_s_setprio(0);
    BARR;

    // ---- ph2 ----
#pragma unroll
    for (int fn = 0; fn < 2; fn++) {
        b23[fn][0] = *(const half8*)(Bb + rB + (2 + fn) * 1024 + cbo0);
        b23[fn][1] = *(const half8*)(Bb + rB + (2 + fn) * 1024 + cbo1);
    }
    if constexpr (MODE == 0) {  // stage A-f0(t+2)
        gload_lds16(aS0 + (size_t)kt2 * 64, Asd + ldA);
        gload_lds16(aS2 + (size_t)kt2 * 64, Asd + 8192 + ldA);
    }
    BARR; LGKM0; SB0;
    __builtin_amdgcn_s_setprio(1);
#pragma unroll
    for (int fm = 0; fm < 4; fm++)
#pragma unroll
        for (int fn = 0; fn < 2; fn++) {
            acc[fm][2 + fn] = MF(a03[fm][0], b23[fn][0], acc[fm][2 + fn]);
            acc[fm][2 + fn] = MF(a03[fm][1], b23[fn][1], acc[fm][2 + fn]);
        }
    __builtin_amdgcn_s_setprio(0);
    BARR;

    // ---- ph3 ----
#pragma unroll
    for (int fm = 0; fm < 4; fm++) {
        a47[fm][0] = *(const half8*)(Ab + rA + (4 + fm) * 1024 + cbo0);
        a47[fm][1] = *(const half8*)(Ab + rA + (4 + fm) * 1024 + cbo1);
    }
    if constexpr (MODE == 0) {  // stage B-n0(t+2)
        gload_lds16(bS0 + (size_t)kt2 * 64, Bsd + sdB);
        gload_lds16(bS2 + (size_t)kt2 * 64, Bsd + 8192 + sdB);
    }
    BARR; LGKM0; SB0;
    __builtin_amdgcn_s_setprio(1);
#pragma unroll
    for (int fm = 0; fm < 4; fm++)
#pragma unroll
        for (int fn = 0; fn < 2; fn++) {
            acc[4 + fm][fn] = MF(a47[fm][0], b01[fn][0], acc[4 + fm][fn]);
            acc[4 + fm][fn] = MF(a47[fm][1], b01[fn][1], acc[4 + fm][fn]);
        }
    __builtin_amdgcn_s_setprio(0);
    BARR;

    // ---- ph4 ----
    if constexpr (MODE == 0) {  // stage A-f1(t+2) + B-n1(t+2)
        gload_lds16(aS1 + (size_t)kt2 * 64, Asd + 4096 + ldA);
        gload_lds16(aS3 + (size_t)kt2 * 64, Asd + 12288 + ldA);
        gload_lds16(bS1 + (size_t)kt2 * 64, Bsd + 2048 + sdB);
        gload_lds16(bS3 + (size_t)kt2 * 64, Bsd + 10240 + sdB);
    }
    __builtin_amdgcn_s_setprio(1);
#pragma unroll
    for (int fm = 0; fm < 4; fm++)
#pragma unroll
        for (int fn = 0; fn < 2; fn++) {
            acc[4 + fm][2 + fn] = MF(a47[fm][0], b23[fn][0], acc[4 + fm][2 + fn]);
            acc[4 + fm][2 + fn] = MF(a47[fm][1], b23[fn][1], acc[4 + fm][2 + fn]);
        }
    __builtin_amdgcn_s_setprio(0);
    if constexpr (MODE == 0) asm volatile("s_waitcnt vmcnt(6)" ::: "memory");
    else if constexpr (MODE == 1) asm volatile("s_waitcnt vmcnt(0)" ::: "memory");
    if constexpr (MODE != 2) BARR;
}

template<int LAYER>
__global__ __launch_bounds__(512, 2) void k_gemm(const _Float16* __restrict__ Ain,
                                                 const _Float16* __restrict__ Bt,
                                                 const float* __restrict__ bias,
                                                 const int* __restrict__ counts,
                                                 const int* __restrict__ offs,
                                                 const int* __restrict__ ltok,
                                                 const float* __restrict__ lw,
                                                 _Float16* __restrict__ Cout) {
    __shared__ _Float16 As[2 * 256 * 64];
    __shared__ _Float16 Bs[2 * 256 * 64];

    // XCD-expert affinity: xs=(x&7)*8+(x>>3); XCD c owns expert c's B panel.
    int xs = (blockIdx.x & 7) * 8 + (blockIdx.x >> 3);
    int e  = xs >> 3;
    int n0 = (xs & 7) * 256;
    int cnt = counts[e];
    int m0 = blockIdx.y * 256;
    if (m0 >= cnt) return;
    int base = offs[e];

    int tid = threadIdx.x;
    int l = tid & 63;
    int wid = tid >> 6;
    int wm = wid >> 2, wn = wid & 3;
    int lr = l & 15, lk = l >> 4;
    int cbo0 = ((lk) ^ (lr & 7)) * 8;
    int cbo1 = ((4 + lk) ^ (lr & 7)) * 8;
    int rA = (wm * 128 + lr) * 64;
    int rB = (wn * 64 + lr) * 64;

    // staging geometry
    int srowA = tid >> 3;                 // 0..63
    int ldA   = tid * 8;                  // A dest (halves), lane-linear
    int srowB = ((wid & 3) * 8) + ((wid >> 2) * 64) + ((l >> 3)); // B row
    int sdB   = srowB * 64 + (l & 7) * 8; // B dest (halves), lane-linear
    size_t koff = (size_t)(((tid & 7) ^ ((tid >> 3) & 7)) * 8);   // pre-swizzled

    const _Float16* aS[4];
#pragma unroll
    for (int j = 0; j < 4; j++) {
        int r = m0 + srowA + j * 64; if (r > cnt - 1) r = cnt - 1;
        if constexpr (LAYER == 1) {
            int tok = ltok[base + r];
            aS[j] = Ain + (size_t)tok * DIM + koff;
        } else {
            aS[j] = Ain + (size_t)(base + r) * HID + koff;
        }
    }
    const int brow[4] = {0, 32, 128, 160};
    const _Float16* bS[4];
#pragma unroll
    for (int j = 0; j < 4; j++)
        bS[j] = Bt + ((size_t)(e * 2048 + n0 + srowB + brow[j])) * 2048 + koff;

    floatx4 acc[8][4];
#pragma unroll
    for (int m = 0; m < 8; m++)
#pragma unroll
        for (int n = 0; n < 4; n++) acc[m][n] = (floatx4){0.f, 0.f, 0.f, 0.f};

    // prologue: tile0 -> buf0 (8 loads), tile1 -> buf1 (8 loads); vmcnt(8): tile0 in.
#pragma unroll
    for (int T = 0; T < 2; T++) {
        _Float16* Ad = As + T * 16384;
        _Float16* Bd = Bs + T * 16384;
        gload_lds16(aS[0] + (size_t)T * 64, Ad + ldA);
        gload_lds16(aS[2] + (size_t)T * 64, Ad + 8192 + ldA);
        gload_lds16(bS[0] + (size_t)T * 64, Bd + sdB);
        gload_lds16(bS[2] + (size_t)T * 64, Bd + 8192 + sdB);
        gload_lds16(aS[1] + (size_t)T * 64, Ad + 4096 + ldA);
        gload_lds16(aS[3] + (size_t)T * 64, Ad + 12288 + ldA);
        gload_lds16(bS[1] + (size_t)T * 64, Bd + 2048 + sdB);
        gload_lds16(bS[3] + (size_t)T * 64, Bd + 10240 + sdB);
    }
    asm volatile("s_waitcnt vmcnt(8)" ::: "memory");
    BARR;

#pragma unroll 1
    for (int t = 0; t < 30; ++t) {
        int b = t & 1;
        tile4<0>(As + b * 16384, Bs + b * 16384, As + b * 16384, Bs + b * 16384,
                 t + 2, aS[0], aS[1], aS[2], aS[3], bS[0], bS[1], bS[2], bS[3],
                 ldA, sdB, rA, rB, cbo0, cbo1, acc);
    }
    tile4<1>(As, Bs, As, Bs, 0, aS[0], aS[1], aS[2], aS[3],
             bS[0], bS[1], bS[2], bS[3], ldA, sdB, rA, rB, cbo0, cbo1, acc);
    tile4<2>(As + 16384, Bs + 16384, As, Bs, 0, aS[0], aS[1], aS[2], aS[3],
             bS[0], bS[1], bS[2], bS[3], ldA, sdB, rA, rB, cbo0, cbo1, acc);

    // epilogue
#pragma unroll
    for (int fm = 0; fm < 8; fm++) {
        int row0 = m0 + wm * 128 + fm * 16 + lk * 4;
#pragma unroll
        for (int fn = 0; fn < 4; fn++) {
            int col = n0 + wn * 64 + fn * 16 + lr;
            float bv = bias[e * 2048 + col];
#pragma unroll
            for (int r = 0; r < 4; r++) {
                int row = row0 + r;
                if (row < cnt) {
                    float v = acc[fm][fn][r] + bv;
                    if constexpr (LAYER == 1) {
                        v = v > 0.f ? v : 0.f;
                    } else {
                        v *= lw[base + row];
                    }
                    Cout[(size_t)(base + row) * HID + col] = (_Float16)v;
                }
            }
        }
    }
}

// ---------------- combine the two weighted expert rows per token ----------------
__global__ __launch_bounds__(256) void k_combine(const _Float16* __restrict__ yb,
                                                 const int* __restrict__ tslot,
                                                 float* __restrict__ out) {
    int t = blockIdx.x;
    int s0 = tslot[2 * t], s1 = tslot[2 * t + 1];
    int c = threadIdx.x * 8;
    half8 y0 = *(const half8*)&yb[(size_t)s0 * HID + c];
    half8 y1 = *(const half8*)&yb[(size_t)s1 * HID + c];
    float* op = out + (size_t)t * HID + c;
    float4 o;
    o.x = (float)y0[0] + (float)y1[0];
    o.y = (float)y0[1] + (float)y1[1];
    o.z = (float)y0[2] + (float)y1[2];
    o.w = (float)y0[3] + (float)y1[3];
    *(float4*)(op) = o;
    o.x = (float)y0[4] + (float)y1[4];
    o.y = (float)y0[5] + (float)y1[5];
    o.z = (float)y0[6] + (float)y1[6];
    o.w = (float)y0[7] + (float)y1[7];
    *(float4*)(op + 4) = o;
}

extern "C" void kernel_launch(void* const* d_in, const int* in_sizes, int n_in,
                              void* d_out, int out_size, void* d_ws, size_t ws_size,
                              hipStream_t stream) {
    const float* x  = (const float*)d_in[0];
    const float* Wg = (const float*)d_in[1];
    const float* bg = (const float*)d_in[2];
    const float* W1 = (const float*)d_in[3];
    const float* b1 = (const float*)d_in[4];
    const float* W2 = (const float*)d_in[5];
    const float* b2 = (const float*)d_in[6];
    float* out = (float*)d_out;

    char* ws = (char*)d_ws;
    _Float16* xh  = (_Float16*)(ws);                       // 33,554,432 B
    _Float16* w1t = (_Float16*)(ws + 33554432ULL);         // 67,108,864 B
    _Float16* w2t = (_Float16*)(ws + 100663296ULL);        // 67,108,864 B
    _Float16* hb  = (_Float16*)(ws + 167772160ULL);        // 67,108,864 B
    _Float16* yb  = (_Float16*)(ws + 234881024ULL);        // 67,108,864 B
    char* rt = ws + 301989888ULL;
    int*   counts = (int*)(rt);             // 8 ints
    int*   fill   = (int*)(rt + 32);        // 8 ints
    int*   offs   = (int*)(rt + 64);        // 9 ints
    int*   te     = (int*)(rt + 128);
    float* tw     = (float*)(rt + 128 + 65536);
    int*   ltok   = (int*)(rt + 128 + 131072);
    float* lw     = (float*)(rt + 128 + 196608);
    int*   tslot  = (int*)(rt + 128 + 262144);

    hipMemsetAsync(rt, 0, 64, stream);  // counts + fill
    k_prep<<<dim3(32, 32, 16), 256, 0, stream>>>(W1, W2, w1t, w2t);
    k_gate<<<512, 256, 0, stream>>>(x, Wg, bg, xh, te, tw, counts);
    k_scan<<<1, 64, 0, stream>>>(counts, offs, fill);
    k_scatter<<<32, 256, 0, stream>>>(te, tw, offs, fill, ltok, lw, tslot);
    k_gemm<1><<<dim3(64, 64), 512, 0, stream>>>(xh, w1t, b1, counts, offs, ltok, nullptr, hb);
    k_gemm<2><<<dim3(64, 64), 512, 0, stream>>>(hb, w2t, b2, counts, offs, ltok, lw, yb);
    k_combine<<<8192, 256, 0, stream>>>(yb, tslot, out);
}

// Round 7
// 608.529 us; speedup vs baseline: 1.4452x; 1.1462x over previous
//
#include <hip/hip_runtime.h>
#include <hip/hip_bf16.h>
#include <cstdint>
#include <cstddef>

#define N_TOK 8192
#define DIM   2048
#define HID   2048
#define NE    8

typedef _Float16 half8  __attribute__((ext_vector_type(8)));
typedef _Float16 half4v __attribute__((ext_vector_type(4)));
typedef float    floatx4 __attribute__((ext_vector_type(4)));

#define BARR  __builtin_amdgcn_s_barrier()
#define SB0   __builtin_amdgcn_sched_barrier(0)
#define LGKM0 asm volatile("s_waitcnt lgkmcnt(0)" ::: "memory")

__device__ inline void gload_lds16(const void* g, void* l) {
    __builtin_amdgcn_global_load_lds(
        (const __attribute__((address_space(1))) unsigned int*)g,
        (__attribute__((address_space(3))) unsigned int*)l, 16, 0, 0);
}

__device__ __forceinline__ floatx4 MF(half8 a, half8 b, floatx4 c) {
    return __builtin_amdgcn_mfma_f32_16x16x32_f16(a, b, c, 0, 0, 0);
}

// ---------------- fused W1+W2 [E][R][C] fp32 -> [E][C][R] fp16 ----------------
__global__ __launch_bounds__(256) void k_prep(const float* __restrict__ W1,
                                              const float* __restrict__ W2,
                                              _Float16* __restrict__ w1t,
                                              _Float16* __restrict__ w2t) {
    __shared__ float tile[64][65];
    int z = blockIdx.z;
    const float* in = (z < 8) ? W1 : W2;
    _Float16* out   = (z < 8) ? w1t : w2t;
    int e  = z & 7;
    int r0 = blockIdx.y * 64;
    int c0 = blockIdx.x * 64;
    int tc = threadIdx.x & 63, tr = threadIdx.x >> 6;
    const float* ip = in + ((size_t)e * 2048 + r0) * 2048 + c0;
#pragma unroll
    for (int i = 0; i < 16; i++)
        tile[tr + i * 4][tc] = ip[(size_t)(tr + i * 4) * 2048 + tc];
    __syncthreads();
    _Float16* op = out + ((size_t)e * 2048 + c0) * 2048 + r0;
#pragma unroll
    for (int i = 0; i < 16; i++) {
        int cc = tr + i * 4;
        op[(size_t)cc * 2048 + tc] = (_Float16)tile[tc][cc];
    }
}

// ---------------- gate: fp64-accum logits, top-2, softmax; fuses x->fp16 ----------------
__global__ __launch_bounds__(256) void k_gate(const float* __restrict__ x,
                                              const float* __restrict__ Wg,
                                              const float* __restrict__ bg,
                                              _Float16* __restrict__ xh,
                                              int* __restrict__ te, float* __restrict__ tw,
                                              int* __restrict__ counts) {
    __shared__ float wgs[NE * DIM]; // 64 KB, transposed [e][d]
    __shared__ int lcnt[NE];
    if (threadIdx.x < NE) lcnt[threadIdx.x] = 0;
    for (int i = threadIdx.x; i < NE * DIM; i += 256)
        wgs[(i & 7) * DIM + (i >> 3)] = Wg[i];
    __syncthreads();
    int wv = threadIdx.x >> 6, l = threadIdx.x & 63;
#pragma unroll 1
    for (int it = 0; it < 4; ++it) {
        int t = blockIdx.x * 16 + wv * 4 + it;
        const float* xr = x + (size_t)t * DIM;
        double acc[NE] = {0, 0, 0, 0, 0, 0, 0, 0};
#pragma unroll 2
        for (int i = 0; i < 8; i++) {
            int d0 = i * 256 + l * 4;
            float4 xv = *(const float4*)(xr + d0);
            half4v hv;
            hv[0] = (_Float16)xv.x; hv[1] = (_Float16)xv.y;
            hv[2] = (_Float16)xv.z; hv[3] = (_Float16)xv.w;
            *(half4v*)(xh + (size_t)t * DIM + d0) = hv;
#pragma unroll
            for (int e = 0; e < NE; e++) {
                float4 w4 = *(const float4*)(wgs + e * DIM + d0);
                acc[e] += (double)xv.x * w4.x + (double)xv.y * w4.y +
                          (double)xv.z * w4.z + (double)xv.w * w4.w;
            }
        }
#pragma unroll
        for (int e = 0; e < NE; e++) {
            double v = acc[e];
            v += __shfl_xor(v, 32, 64); v += __shfl_xor(v, 16, 64);
            v += __shfl_xor(v, 8, 64);  v += __shfl_xor(v, 4, 64);
            v += __shfl_xor(v, 2, 64);  v += __shfl_xor(v, 1, 64);
            acc[e] = v;
        }
        if (l == 0) {
            double best0 = -1e300, best1 = -1e300; int i0 = 0, i1 = 0;
#pragma unroll
            for (int e = 0; e < NE; e++) {
                double lg = acc[e] + (double)bg[e];
                if (lg > best0) { best1 = best0; i1 = i0; best0 = lg; i0 = e; }
                else if (lg > best1) { best1 = lg; i1 = e; }
            }
            float d  = expf((float)(best1 - best0));
            float w0 = 1.f / (1.f + d), w1 = d / (1.f + d);
            te[2 * t] = i0; te[2 * t + 1] = i1;
            tw[2 * t] = w0; tw[2 * t + 1] = w1;
            atomicAdd(&lcnt[i0], 1);
            atomicAdd(&lcnt[i1], 1);
        }
    }
    __syncthreads();
    if (threadIdx.x < NE) atomicAdd(&counts[threadIdx.x], lcnt[threadIdx.x]);
}

// ---------------- tiny scan ----------------
__global__ void k_scan(const int* __restrict__ counts, int* __restrict__ offs,
                       int* __restrict__ fill) {
    if (threadIdx.x == 0 && blockIdx.x == 0) {
        int s = 0;
        for (int e = 0; e < NE; e++) { offs[e] = s; s += counts[e]; fill[e] = 0; }
        offs[NE] = s;
    }
}

// ---------------- scatter tokens to expert lists ----------------
__global__ __launch_bounds__(256) void k_scatter(const int* __restrict__ te,
                                                 const float* __restrict__ tw,
                                                 const int* __restrict__ offs,
                                                 int* __restrict__ fill,
                                                 int* __restrict__ ltok,
                                                 float* __restrict__ lw,
                                                 int* __restrict__ tslot) {
    int t = blockIdx.x * blockDim.x + threadIdx.x;
    if (t >= N_TOK) return;
#pragma unroll
    for (int k = 0; k < 2; k++) {
        int e = te[2 * t + k];
        int p = atomicAdd(&fill[e], 1);
        int idx = offs[e] + p;
        ltok[idx] = t; lw[idx] = tw[2 * t + k]; tslot[2 * t + k] = idx;
    }
}

// ============ barrier-light kk-pipelined GEMM: BM=BN=256, BK=64 ============
// 512 thr = 8 waves (2m x 4n); wave tile 128x64; acc[8][4] of 16x16x32_f16.
// LDS: As[2][256][64] + Bs[2][256][64] fp16 = 128 KB; tile t -> buf t&1.
// Per K-tile (2 barriers only):
//   issue ALL 24 ds_read_b128 (kk0 set first, kk1 second)    [plain loads:
//   compiler emits counted lgkmcnt per use -> kk1 drains under MFMA kk0]
//   MFMA kk0 (32) ; LGKM0 ; BARR    <- all waves done reading buf b
//   stage tile t+2 -> buf b (8 gload_lds) ; SB0
//   MFMA kk1 (32)                    <- hides stage issue
//   vmcnt(8) ; BARR                  <- tile t+1 (staged 1 tile ago, ~3000cyc)
//                                       proven landed; t+2's 8 stay in flight
// XOR swizzle (both-sides, rule 21): physical 16B chunk = logical ^ (row&7);
// staged via pre-swizzled global source column + lane-linear gload_lds dest.

template<int MODE>  // 0: stage+vmcnt(8); 1: no stage, vmcnt(0); 2: last tile
__device__ __forceinline__ void tileX(
    const _Float16* __restrict__ Ab, const _Float16* __restrict__ Bb,
    _Float16* Asd, _Float16* Bsd, int kt2,
    const _Float16* aS0, const _Float16* aS1, const _Float16* aS2, const _Float16* aS3,
    const _Float16* bS0, const _Float16* bS1, const _Float16* bS2, const _Float16* bS3,
    int ldA, int sdB, int rA, int rB, int cbo0, int cbo1,
    floatx4 (&acc)[8][4])
{
    half8 a0[8], a1[8], b0[4], b1[4];
#pragma unroll
    for (int fm = 0; fm < 8; fm++) a0[fm] = *(const half8*)(Ab + rA + fm * 1024 + cbo0);
#pragma unroll
    for (int fn = 0; fn < 4; fn++) b0[fn] = *(const half8*)(Bb + rB + fn * 1024 + cbo0);
#pragma unroll
    for (int fm = 0; fm < 8; fm++) a1[fm] = *(const half8*)(Ab + rA + fm * 1024 + cbo1);
#pragma unroll
    for (int fn = 0; fn < 4; fn++) b1[fn] = *(const half8*)(Bb + rB + fn * 1024 + cbo1);

    __builtin_amdgcn_s_setprio(1);
#pragma unroll
    for (int fm = 0; fm < 8; fm++)
#pragma unroll
        for (int fn = 0; fn < 4; fn++)
            acc[fm][fn] = MF(a0[fm], b0[fn], acc[fm][fn]);
    __builtin_amdgcn_s_setprio(0);

    LGKM0;   // all 24 reads of buf b retired (kk1 drained under kk0 MFMA)
    BARR;    // all waves finished reading buf b -> safe to overwrite

    if constexpr (MODE == 0) {
        gload_lds16(aS0 + (size_t)kt2 * 64, Asd + ldA);
        gload_lds16(aS1 + (size_t)kt2 * 64, Asd + 4096 + ldA);
        gload_lds16(aS2 + (size_t)kt2 * 64, Asd + 8192 + ldA);
        gload_lds16(aS3 + (size_t)kt2 * 64, Asd + 12288 + ldA);
        gload_lds16(bS0 + (size_t)kt2 * 64, Bsd + sdB);
        gload_lds16(bS1 + (size_t)kt2 * 64, Bsd + 2048 + sdB);
        gload_lds16(bS2 + (size_t)kt2 * 64, Bsd + 8192 + sdB);
        gload_lds16(bS3 + (size_t)kt2 * 64, Bsd + 10240 + sdB);
        SB0;
    }

    __builtin_amdgcn_s_setprio(1);
#pragma unroll
    for (int fm = 0; fm < 8; fm++)
#pragma unroll
        for (int fn = 0; fn < 4; fn++)
            acc[fm][fn] = MF(a1[fm], b1[fn], acc[fm][fn]);
    __builtin_amdgcn_s_setprio(0);

    if constexpr (MODE == 0) asm volatile("s_waitcnt vmcnt(8)" ::: "memory");
    else if constexpr (MODE == 1) asm volatile("s_waitcnt vmcnt(0)" ::: "memory");
    if constexpr (MODE != 2) BARR;
}

template<int LAYER>
__global__ __launch_bounds__(512, 2) void k_gemm(const _Float16* __restrict__ Ain,
                                                 const _Float16* __restrict__ Bt,
                                                 const float* __restrict__ bias,
                                                 const int* __restrict__ counts,
                                                 const int* __restrict__ offs,
                                                 const int* __restrict__ ltok,
                                                 const float* __restrict__ lw,
                                                 _Float16* __restrict__ Cout) {
    __shared__ _Float16 As[2 * 256 * 64];
    __shared__ _Float16 Bs[2 * 256 * 64];

    // XCD-expert affinity: xs=(x&7)*8+(x>>3); XCD c owns expert c's B panel.
    int xs = (blockIdx.x & 7) * 8 + (blockIdx.x >> 3);
    int e  = xs >> 3;
    int n0 = (xs & 7) * 256;
    int cnt = counts[e];
    int m0 = blockIdx.y * 256;
    if (m0 >= cnt) return;
    int base = offs[e];

    int tid = threadIdx.x;
    int l = tid & 63;
    int wid = tid >> 6;
    int wm = wid >> 2, wn = wid & 3;
    int lr = l & 15, lk = l >> 4;
    int cbo0 = ((lk) ^ (lr & 7)) * 8;
    int cbo1 = ((4 + lk) ^ (lr & 7)) * 8;
    int rA = (wm * 128 + lr) * 64;
    int rB = (wn * 64 + lr) * 64;

    // staging geometry (lane-linear 16B dest within each wave - m104-safe)
    int srowA = tid >> 3;                 // 0..63
    int ldA   = tid * 8;                  // A dest (halves)
    int srowB = ((wid & 3) * 8) + ((wid >> 2) * 64) + ((l >> 3)); // B row
    int sdB   = srowB * 64 + (l & 7) * 8; // B dest (halves)
    size_t koff = (size_t)(((tid & 7) ^ ((tid >> 3) & 7)) * 8);   // pre-swizzled

    const _Float16* aS[4];
#pragma unroll
    for (int j = 0; j < 4; j++) {
        int r = m0 + srowA + j * 64; if (r > cnt - 1) r = cnt - 1;
        if constexpr (LAYER == 1) {
            int tok = ltok[base + r];
            aS[j] = Ain + (size_t)tok * DIM + koff;
        } else {
            aS[j] = Ain + (size_t)(base + r) * HID + koff;
        }
    }
    const int brow[4] = {0, 32, 128, 160};
    const _Float16* bS[4];
#pragma unroll
    for (int j = 0; j < 4; j++)
        bS[j] = Bt + ((size_t)(e * 2048 + n0 + srowB + brow[j])) * 2048 + koff;

    floatx4 acc[8][4];
#pragma unroll
    for (int m = 0; m < 8; m++)
#pragma unroll
        for (int n = 0; n < 4; n++) acc[m][n] = (floatx4){0.f, 0.f, 0.f, 0.f};

    // prologue: tile0 -> buf0 (8 loads), tile1 -> buf1 (8 loads); vmcnt(8): tile0 in.
#pragma unroll
    for (int T = 0; T < 2; T++) {
        _Float16* Ad = As + T * 16384;
        _Float16* Bd = Bs + T * 16384;
        gload_lds16(aS[0] + (size_t)T * 64, Ad + ldA);
        gload_lds16(aS[1] + (size_t)T * 64, Ad + 4096 + ldA);
        gload_lds16(aS[2] + (size_t)T * 64, Ad + 8192 + ldA);
        gload_lds16(aS[3] + (size_t)T * 64, Ad + 12288 + ldA);
        gload_lds16(bS[0] + (size_t)T * 64, Bd + sdB);
        gload_lds16(bS[1] + (size_t)T * 64, Bd + 2048 + sdB);
        gload_lds16(bS[2] + (size_t)T * 64, Bd + 8192 + sdB);
        gload_lds16(bS[3] + (size_t)T * 64, Bd + 10240 + sdB);
    }
    asm volatile("s_waitcnt vmcnt(8)" ::: "memory");
    BARR;

#pragma unroll 1
    for (int t = 0; t < 30; ++t) {
        int b = t & 1;
        tileX<0>(As + b * 16384, Bs + b * 16384, As + b * 16384, Bs + b * 16384,
                 t + 2, aS[0], aS[1], aS[2], aS[3], bS[0], bS[1], bS[2], bS[3],
                 ldA, sdB, rA, rB, cbo0, cbo1, acc);
    }
    tileX<1>(As, Bs, As, Bs, 0, aS[0], aS[1], aS[2], aS[3],
             bS[0], bS[1], bS[2], bS[3], ldA, sdB, rA, rB, cbo0, cbo1, acc);
    tileX<2>(As + 16384, Bs + 16384, As, Bs, 0, aS[0], aS[1], aS[2], aS[3],
             bS[0], bS[1], bS[2], bS[3], ldA, sdB, rA, rB, cbo0, cbo1, acc);

    // epilogue
#pragma unroll
    for (int fm = 0; fm < 8; fm++) {
        int row0 = m0 + wm * 128 + fm * 16 + lk * 4;
#pragma unroll
        for (int fn = 0; fn < 4; fn++) {
            int col = n0 + wn * 64 + fn * 16 + lr;
            float bv = bias[e * 2048 + col];
#pragma unroll
            for (int r = 0; r < 4; r++) {
                int row = row0 + r;
                if (row < cnt) {
                    float v = acc[fm][fn][r] + bv;
                    if constexpr (LAYER == 1) {
                        v = v > 0.f ? v : 0.f;
                    } else {
                        v *= lw[base + row];
                    }
                    Cout[(size_t)(base + row) * HID + col] = (_Float16)v;
                }
            }
        }
    }
}

// ---------------- combine the two weighted expert rows per token ----------------
__global__ __launch_bounds__(256) void k_combine(const _Float16* __restrict__ yb,
                                                 const int* __restrict__ tslot,
                                                 float* __restrict__ out) {
    int t = blockIdx.x;
    int s0 = tslot[2 * t], s1 = tslot[2 * t + 1];
    int c = threadIdx.x * 8;
    half8 y0 = *(const half8*)&yb[(size_t)s0 * HID + c];
    half8 y1 = *(const half8*)&yb[(size_t)s1 * HID + c];
    float* op = out + (size_t)t * HID + c;
    float4 o;
    o.x = (float)y0[0] + (float)y1[0];
    o.y = (float)y0[1] + (float)y1[1];
    o.z = (float)y0[2] + (float)y1[2];
    o.w = (float)y0[3] + (float)y1[3];
    *(float4*)(op) = o;
    o.x = (float)y0[4] + (float)y1[4];
    o.y = (float)y0[5] + (float)y1[5];
    o.z = (float)y0[6] + (float)y1[6];
    o.w = (float)y0[7] + (float)y1[7];
    *(float4*)(op + 4) = o;
}

extern "C" void kernel_launch(void* const* d_in, const int* in_sizes, int n_in,
                              void* d_out, int out_size, void* d_ws, size_t ws_size,
                              hipStream_t stream) {
    const float* x  = (const float*)d_in[0];
    const float* Wg = (const float*)d_in[1];
    const float* bg = (const float*)d_in[2];
    const float* W1 = (const float*)d_in[3];
    const float* b1 = (const float*)d_in[4];
    const float* W2 = (const float*)d_in[5];
    const float* b2 = (const float*)d_in[6];
    float* out = (float*)d_out;

    char* ws = (char*)d_ws;
    _Float16* xh  = (_Float16*)(ws);                       // 33,554,432 B
    _Float16* w1t = (_Float16*)(ws + 33554432ULL);         // 67,108,864 B
    _Float16* w2t = (_Float16*)(ws + 100663296ULL);        // 67,108,864 B
    _Float16* hb  = (_Float16*)(ws + 167772160ULL);        // 67,108,864 B
    _Float16* yb  = (_Float16*)(ws + 234881024ULL);        // 67,108,864 B
    char* rt = ws + 301989888ULL;
    int*   counts = (int*)(rt);             // 8 ints
    int*   fill   = (int*)(rt + 32);        // 8 ints
    int*   offs   = (int*)(rt + 64);        // 9 ints
    int*   te     = (int*)(rt + 128);
    float* tw     = (float*)(rt + 128 + 65536);
    int*   ltok   = (int*)(rt + 128 + 131072);
    float* lw     = (float*)(rt + 128 + 196608);
    int*   tslot  = (int*)(rt + 128 + 262144);

    hipMemsetAsync(rt, 0, 64, stream);  // counts + fill
    k_prep<<<dim3(32, 32, 16), 256, 0, stream>>>(W1, W2, w1t, w2t);
    k_gate<<<512, 256, 0, stream>>>(x, Wg, bg, xh, te, tw, counts);
    k_scan<<<1, 64, 0, stream>>>(counts, offs, fill);
    k_scatter<<<32, 256, 0, stream>>>(te, tw, offs, fill, ltok, lw, tslot);
    k_gemm<1><<<dim3(64, 32), 512, 0, stream>>>(xh, w1t, b1, counts, offs, ltok, nullptr, hb);
    k_gemm<2><<<dim3(64, 32), 512, 0, stream>>>(hb, w2t, b2, counts, offs, ltok, lw, yb);
    k_combine<<<8192, 256, 0, stream>>>(yb, tslot, out);
}